// Round 15
// baseline (186.303 us; speedup 1.0000x reference)
//
#include <hip/hip_runtime.h>
#include <stdint.h>

typedef __bf16 bf16x8 __attribute__((ext_vector_type(8)));
typedef float f32x4 __attribute__((ext_vector_type(4)));

#define NSAMPLE 64
static constexpr int Bb = 4, Nn = 16384, Mm = 1024, Cc = 256;
static constexpr int K1P = 288;   // layer-1 K: 256 features + 3 coords + pad (9 x 32)

__device__ __forceinline__ unsigned short f2bf(float f) {
  unsigned int u = __builtin_bit_cast(unsigned int, f);
  u = u + 0x7fffu + ((u >> 16) & 1u);
  return (unsigned short)(u >> 16);
}

// async global->LDS, 16B per lane; LDS dest = wave-uniform base + lane*16
__device__ __forceinline__ void gload_lds16(const void* g, void* lds) {
  __builtin_amdgcn_global_load_lds(
      (const __attribute__((address_space(1))) uint32_t*)g,
      (__attribute__((address_space(3))) uint32_t*)lds, 16, 0, 0);
}

// ---------------- xyz -> float4 (x,y,z,|p|^2) — separate launch: ballq (next kernel) consumes it
__global__ void xyzw_kernel(const float* __restrict__ xyz, float4* __restrict__ xyzw) {
  int t = blockIdx.x * 256 + threadIdx.x;
  float x = xyz[t * 3], y = xyz[t * 3 + 1], z = xyz[t * 3 + 2];
  float pp = __fadd_rn(__fadd_rn(__fmul_rn(x, x), __fmul_rn(y, y)), __fmul_rn(z, z));
  xyzw[t] = make_float4(x, y, z, pp);
}

// ---- prep + ballq + featsT merged at BLOCK level (all outputs consumed by LATER kernels only,
// ---- except xyzw->ballq which comes from the prior launch). blocks 0..287: prep (R1-verbatim);
// ---- 288..4383: ballq (R14 split-scan verbatim); 4384..8479: featsT (R8-verbatim).
__global__ void prep_featsT_ballq_kernel(
    const float* __restrict__ W1, const float* __restrict__ b1,
    const float* __restrict__ g1, const float* __restrict__ be1,
    const float* __restrict__ m1, const float* __restrict__ v1,
    const float* __restrict__ W2, const float* __restrict__ b2,
    const float* __restrict__ g2, const float* __restrict__ be2,
    const float* __restrict__ m2, const float* __restrict__ v2,
    unsigned short* __restrict__ W1b, float* __restrict__ b1e,
    unsigned short* __restrict__ W2b, float* __restrict__ b2e,
    const float* __restrict__ feats, unsigned short* __restrict__ featsT,
    const float4* __restrict__ xyzw, const float* __restrict__ new_xyz,
    int* __restrict__ idx) {
  __shared__ float tile[64][65];
  __shared__ int wl[4][64];
  __shared__ int wcnt[4];
  int bx = blockIdx.x;
  int t = threadIdx.x;
  if (bx < 288) {
    // ---------------- prep body (R1 verbatim) ----------------
    int g = bx * 256 + t;
    if (g < 256 * K1P) {
      int o = g / K1P, k = g - o * K1P;
      float s = g1[o] / sqrtf(v1[o] + 1e-5f);
      float w = 0.f;
      if (k < 256) w = W1[o * 259 + 3 + k];
      else if (k < 259) w = W1[o * 259 + (k - 256)];
      W1b[g] = f2bf(w * s);
    }
    if (g < 256 * 256) {
      int o = g >> 8;
      float s = g2[o] / sqrtf(v2[o] + 1e-5f);
      W2b[g] = f2bf(W2[g] * s);
    }
    if (g < 256) {
      float s1 = g1[g] / sqrtf(v1[g] + 1e-5f);
      b1e[g] = s1 * (b1[g] - m1[g]) + be1[g];
      float s2 = g2[g] / sqrtf(v2[g] + 1e-5f);
      b2e[g] = s2 * (b2[g] - m2[g]) + be2[g];
    }
    return;
  }
  if (bx < 288 + 4096) {
    // ---------------- ballq: split-scan, R14 verbatim ----------------
    const float r2 = (float)(0.08 * 0.08);
    int bm = bx - 288;
    int lane = t & 63, w = t >> 6;
    int b = bm >> 10;
    float qx = new_xyz[bm * 3], qy = new_xyz[bm * 3 + 1], qz = new_xyz[bm * 3 + 2];
    float qq = __fadd_rn(__fadd_rn(__fmul_rn(qx, qx), __fmul_rn(qy, qy)), __fmul_rn(qz, qz));
    const float4* P = xyzw + (size_t)b * Nn + w * 4096;
    int cnt = 0;
    for (int n0 = 0; n0 < 4096; n0 += 64) {
      float4 p = P[n0 + lane];
      float dt = __fadd_rn(__fadd_rn(__fmul_rn(qx, p.x), __fmul_rn(qy, p.y)), __fmul_rn(qz, p.z));
      float d2 = __fsub_rn(__fadd_rn(qq, p.w), __fmul_rn(2.f, dt));
      bool valid = d2 < r2;
      unsigned long long mask = __ballot(valid);
      if (mask) {
        if (valid) {
          int pos = cnt + __popcll(mask & ((1ull << lane) - 1ull));
          if (pos < NSAMPLE) wl[w][pos] = w * 4096 + n0 + lane;
        }
        cnt += (int)__popcll(mask);
        if (cnt >= NSAMPLE) break;
      }
    }
    if (lane == 0) wcnt[w] = cnt;
    __syncthreads();
    if (t < NSAMPLE) {
      int c0 = wcnt[0], c1 = wcnt[1], c2 = wcnt[2], c3 = wcnt[3];
      int tot = c0 + c1 + c2 + c3;
      int cc = tot < NSAMPLE ? tot : NSAMPLE;
      int v;
      if (t < cc) {
        if (t < c0) v = wl[0][t];
        else if (t < c0 + c1) v = wl[1][t - c0];
        else if (t < c0 + c1 + c2) v = wl[2][t - c0 - c1];
        else v = wl[3][t - c0 - c1 - c2];
      } else {
        v = (c0 > 0) ? wl[0][0] : (c1 > 0) ? wl[1][0] : (c2 > 0) ? wl[2][0] : (c3 > 0) ? wl[3][0] : 0;
      }
      idx[(size_t)bm * NSAMPLE + t] = v;
    }
    return;
  }
  // ---------------- featsT — R8 verbatim body ----------------
  int fb = bx - (288 + 4096);     // 0..4095
  int b = fb >> 10;
  int rem = fb & 1023;
  int nt = rem >> 2, ct = rem & 3;
  int tx = t & 63, ty = t >> 6;
  const float* src = feats + ((size_t)b * Cc + ct * 64) * Nn + nt * 64;
#pragma unroll
  for (int i = 0; i < 16; i++) {
    int c = i * 4 + ty;
    tile[c][tx] = src[(size_t)c * Nn + tx];
  }
  __syncthreads();
  unsigned short* dst = featsT + ((size_t)b * Nn + nt * 64) * Cc + ct * 64;
  int c4 = (t & 15) * 4, n0 = t >> 4;
#pragma unroll
  for (int i = 0; i < 4; i++) {
    int n = i * 16 + n0;
    ushort4 v;
    v.x = f2bf(tile[c4][n]);
    v.y = f2bf(tile[c4 + 1][n]);
    v.z = f2bf(tile[c4 + 2][n]);
    v.w = f2bf(tile[c4 + 3][n]);
    *(ushort4*)&dst[(size_t)n * Cc + c4] = v;
  }
}

// ---------------- fused: 2 queries/block, 8 waves (2 M-groups x 4 N-groups), R12 internals ----
// M-tile = 128 rows (2 queries x 64 samples). Wave (mg,ng) computes rows [mg*64,mg*64+64) x cols
// [ng*64,ng*64+64). Waves sharing ng issue identical W addresses -> L1/L2 dedup halves W traffic.
// Xf[128][256] swizzled (chunk c^(r&7), inverse on global side); H aliases Xf; Xco[128][40] coord
// K-chunk. Per-wave reg footprint identical to R12 (same 4x4 acc) -> (512,4) caps 128 total/wave.
__global__ __launch_bounds__(512, 4) void fused_kernel(
    const unsigned short* __restrict__ featsT, const float4* __restrict__ xyzw,
    const float* __restrict__ new_xyz, const int* __restrict__ idx,
    const unsigned short* __restrict__ W1b, const float* __restrict__ b1e,
    const unsigned short* __restrict__ W2b, const float* __restrict__ b2e,
    float* __restrict__ out) {
  __shared__ unsigned short Xf[128 * 256];  // 65536 B
  __shared__ unsigned short Xco[128 * 40];  // 10240 B
  int t = threadIdx.x;
  int wave = t >> 6, lane = t & 63;
  int lr = lane & 15, kg = lane >> 4;
  int mg = wave >> 2, ng = wave & 3;
  int wcol = ng * 64, mrow = mg * 64;
  int bm0 = blockIdx.x * 2;
  int b = bm0 >> 10;  // 2 | 1024: block never crosses batches

  // ---- prologue: coord rows (thread t -> global row t) + async swizzled gather ----
  if (t < 128) {
    int qm = bm0 + (t >> 6);
    int ci = idx[(size_t)qm * NSAMPLE + (t & 63)];
    float4 p = xyzw[(size_t)b * Nn + ci];
    unsigned int c01 = (unsigned int)f2bf(p.x - new_xyz[qm * 3])
                     | ((unsigned int)f2bf(p.y - new_xyz[qm * 3 + 1]) << 16);
    unsigned int c2 = (unsigned int)f2bf(p.z - new_xyz[qm * 3 + 2]);
    uint4 v0 = make_uint4(c01, c2, 0u, 0u);
    uint4 z = make_uint4(0u, 0u, 0u, 0u);
    uint4* row = (uint4*)&Xco[t * 40];
    row[0] = v0; row[1] = z; row[2] = z; row[3] = z; row[4] = z;
  }
  {
    // wave w covers global rows [w*16, w*16+16) = query bm0+(w>>2), samples (w&3)*16 + 0..15
    int idxr = idx[(size_t)(bm0 + (wave >> 2)) * NSAMPLE + (wave & 3) * 16 + (lane & 15)];
#pragma unroll
    for (int i = 0; i < 8; i++) {
      int j = wave * 8 + i;                       // row pair 2j, 2j+1 (global rows 0..127)
      int iv = __shfl(idxr, 2 * i + (lane >> 5));
      int r7 = (2 * j + (lane >> 5)) & 7;
      int cg = (lane & 31) ^ r7;                  // swizzled global chunk (rule #21)
      gload_lds16(featsT + ((size_t)b * Nn + iv) * Cc + cg * 8, &Xf[j * 512]);
    }
  }
  __syncthreads();

  // ---- layer 1: [128x288]x[288x256]; kk 0..7 from Xf (swizzled), kk 8 from Xco ----
  f32x4 acc[4][4];
#pragma unroll
  for (int mi = 0; mi < 4; mi++)
#pragma unroll
    for (int ni = 0; ni < 4; ni++) acc[mi][ni] = (f32x4){0.f, 0.f, 0.f, 0.f};
#pragma unroll
  for (int kk = 0; kk < 9; kk++) {
    bf16x8 w[4];
#pragma unroll
    for (int ni = 0; ni < 4; ni++)
      w[ni] = *(const bf16x8*)&W1b[(size_t)(wcol + ni * 16 + lr) * K1P + kk * 32 + kg * 8];
    bf16x8 a[4];
#pragma unroll
    for (int mi = 0; mi < 4; mi++) {
      int r = mrow + mi * 16 + lr;
      if (kk < 8) {
        int cs = ((kk * 4 + kg) ^ (r & 7)) * 8;
        a[mi] = *(const bf16x8*)&Xf[r * 256 + cs];
      } else {
        a[mi] = *(const bf16x8*)&Xco[r * 40 + kg * 8];
      }
    }
    __builtin_amdgcn_s_setprio(1);
#pragma unroll
    for (int mi = 0; mi < 4; mi++)
#pragma unroll
      for (int ni = 0; ni < 4; ni++)
        acc[mi][ni] = __builtin_amdgcn_mfma_f32_16x16x32_bf16(a[mi], w[ni], acc[mi][ni], 0, 0, 0);
    __builtin_amdgcn_s_setprio(0);
  }
  __syncthreads();  // B3: all waves done reading Xf

  // ---- epilogue 1 (thin): bias + relu -> H (aliases Xf, swizzled store) ----
#pragma unroll
  for (int ni = 0; ni < 4; ni++) {
    int o = wcol + ni * 16 + lr;
    float bb = b1e[o];
#pragma unroll
    for (int mi = 0; mi < 4; mi++)
#pragma unroll
      for (int j = 0; j < 4; j++) {
        int r = mrow + mi * 16 + kg * 4 + j;
        float h = fmaxf(acc[mi][ni][j] + bb, 0.f);
        Xf[r * 256 + ((((o >> 3) ^ (r & 7)) << 3) + (o & 7))] = f2bf(h);
      }
  }
  __syncthreads();  // B4: H visible

  // ---- layer 2: [128x256]x[256x256] from H (same swizzle) ----
#pragma unroll
  for (int mi = 0; mi < 4; mi++)
#pragma unroll
    for (int ni = 0; ni < 4; ni++) acc[mi][ni] = (f32x4){0.f, 0.f, 0.f, 0.f};
#pragma unroll
  for (int kk = 0; kk < 8; kk++) {
    bf16x8 w[4];
#pragma unroll
    for (int ni = 0; ni < 4; ni++)
      w[ni] = *(const bf16x8*)&W2b[(size_t)(wcol + ni * 16 + lr) * 256 + kk * 32 + kg * 8];
    bf16x8 a[4];
#pragma unroll
    for (int mi = 0; mi < 4; mi++) {
      int r = mrow + mi * 16 + lr;
      int cs = ((kk * 4 + kg) ^ (r & 7)) * 8;
      a[mi] = *(const bf16x8*)&Xf[r * 256 + cs];
    }
    __builtin_amdgcn_s_setprio(1);
#pragma unroll
    for (int mi = 0; mi < 4; mi++)
#pragma unroll
      for (int ni = 0; ni < 4; ni++)
        acc[mi][ni] = __builtin_amdgcn_mfma_f32_16x16x32_bf16(a[mi], w[ni], acc[mi][ni], 0, 0, 0);
    __builtin_amdgcn_s_setprio(0);
  }
  // ---- epilogue 2: bias + relu + max over this query's 64 samples -> out[b][o][m] ----
  {
    int m = (bm0 + mg) & (Mm - 1);
#pragma unroll
    for (int ni = 0; ni < 4; ni++) {
      float bv = b2e[wcol + ni * 16 + lr];
      float v = 0.f;  // relu(max) == max(relu)
#pragma unroll
      for (int mi = 0; mi < 4; mi++)
#pragma unroll
        for (int j = 0; j < 4; j++) v = fmaxf(v, acc[mi][ni][j] + bv);
      v = fmaxf(v, __shfl_xor(v, 16));
      v = fmaxf(v, __shfl_xor(v, 32));
      if (kg == 0)
        out[((size_t)b * 256 + wcol + ni * 16 + lr) * Mm + m] = v;
    }
  }
}

extern "C" void kernel_launch(void* const* d_in, const int* in_sizes, int n_in,
                              void* d_out, int out_size, void* d_ws, size_t ws_size,
                              hipStream_t stream) {
  (void)in_sizes; (void)n_in; (void)out_size; (void)ws_size;
  const float* xyz     = (const float*)d_in[0];
  const float* new_xyz = (const float*)d_in[1];
  const float* feats   = (const float*)d_in[2];
  const float* W1 = (const float*)d_in[3];
  const float* b1 = (const float*)d_in[4];
  const float* g1 = (const float*)d_in[5];
  const float* be1 = (const float*)d_in[6];
  const float* m1 = (const float*)d_in[7];
  const float* v1 = (const float*)d_in[8];
  const float* W2 = (const float*)d_in[9];
  const float* b2 = (const float*)d_in[10];
  const float* g2 = (const float*)d_in[11];
  const float* be2 = (const float*)d_in[12];
  const float* m2 = (const float*)d_in[13];
  const float* v2 = (const float*)d_in[14];
  float* out = (float*)d_out;

  char* ws = (char*)d_ws;
  unsigned short* W1b   = (unsigned short*)(ws + 0);         // 147456 B ([256][288])
  unsigned short* W2b   = (unsigned short*)(ws + 147456);    // 131072 B
  float*          b1e   = (float*)(ws + 278528);             // 1024 B
  float*          b2e   = (float*)(ws + 279552);             // 1024 B
  float4*         xyzw  = (float4*)(ws + 280576);            // 1048576 B
  unsigned short* featsT= (unsigned short*)(ws + 1329152);   // 33554432 B
  int*            idx   = (int*)(ws + 34883584);             // 1048576 B

  xyzw_kernel<<<(Bb * Nn) / 256, 256, 0, stream>>>(xyz, xyzw);
  prep_featsT_ballq_kernel<<<288 + 4096 + 4096, 256, 0, stream>>>(
      W1, b1, g1, be1, m1, v1, W2, b2, g2, be2, m2, v2,
      W1b, b1e, W2b, b2e, feats, featsT, xyzw, new_xyz, idx);
  fused_kernel<<<(Bb * Mm) / 2, 512, 0, stream>>>(featsT, xyzw, new_xyz, idx,
                                                  W1b, b1e, W2b, b2e, out);
}

// Round 16
// 183.998 us; speedup vs baseline: 1.0125x; 1.0125x over previous
//
#include <hip/hip_runtime.h>
#include <stdint.h>

typedef __bf16 bf16x8 __attribute__((ext_vector_type(8)));
typedef float f32x4 __attribute__((ext_vector_type(4)));

#define NSAMPLE 64
static constexpr int Bb = 4, Nn = 16384, Mm = 1024, Cc = 256;
static constexpr int K1P = 288;   // layer-1 K: 256 features + 3 coords + pad (9 x 32)

__device__ __forceinline__ unsigned short f2bf(float f) {
  unsigned int u = __builtin_bit_cast(unsigned int, f);
  u = u + 0x7fffu + ((u >> 16) & 1u);
  return (unsigned short)(u >> 16);
}

// async global->LDS, 16B per lane; LDS dest = wave-uniform base + lane*16
__device__ __forceinline__ void gload_lds16(const void* g, void* lds) {
  __builtin_amdgcn_global_load_lds(
      (const __attribute__((address_space(1))) uint32_t*)g,
      (__attribute__((address_space(3))) uint32_t*)lds, 16, 0, 0);
}

// ---- prep + xyzw merged at BLOCK level (R14 verbatim): blocks 0..287 prep, 288..543 xyzw ----
__global__ void prep_xyzw_kernel(const float* __restrict__ W1, const float* __restrict__ b1,
                                 const float* __restrict__ g1, const float* __restrict__ be1,
                                 const float* __restrict__ m1, const float* __restrict__ v1,
                                 const float* __restrict__ W2, const float* __restrict__ b2,
                                 const float* __restrict__ g2, const float* __restrict__ be2,
                                 const float* __restrict__ m2, const float* __restrict__ v2,
                                 const float* __restrict__ xyz,
                                 unsigned short* __restrict__ W1b, float* __restrict__ b1e,
                                 unsigned short* __restrict__ W2b, float* __restrict__ b2e,
                                 float4* __restrict__ xyzw) {
  int bx = blockIdx.x;
  if (bx < 288) {
    int t = bx * 256 + threadIdx.x;
    if (t < 256 * K1P) {
      int o = t / K1P, k = t - o * K1P;
      float s = g1[o] / sqrtf(v1[o] + 1e-5f);
      float w = 0.f;
      if (k < 256) w = W1[o * 259 + 3 + k];
      else if (k < 259) w = W1[o * 259 + (k - 256)];
      W1b[t] = f2bf(w * s);
    }
    if (t < 256 * 256) {
      int o = t >> 8;
      float s = g2[o] / sqrtf(v2[o] + 1e-5f);
      W2b[t] = f2bf(W2[t] * s);
    }
    if (t < 256) {
      float s1 = g1[t] / sqrtf(v1[t] + 1e-5f);
      b1e[t] = s1 * (b1[t] - m1[t]) + be1[t];
      float s2 = g2[t] / sqrtf(v2[t] + 1e-5f);
      b2e[t] = s2 * (b2[t] - m2[t]) + be2[t];
    }
    return;
  }
  int t = (bx - 288) * 256 + threadIdx.x;  // 0..65535
  float x = xyz[t * 3], y = xyz[t * 3 + 1], z = xyz[t * 3 + 2];
  float pp = __fadd_rn(__fadd_rn(__fmul_rn(x, x), __fmul_rn(y, y)), __fmul_rn(z, z));
  xyzw[t] = make_float4(x, y, z, pp);
}

// ---- featsT + ballq merged at BLOCK level (R14 verbatim): 0..4095 ballq split-scan,
// ---- 4096..8191 featsT ----
__global__ void featsT_ballq_kernel(const float* __restrict__ feats,
                                    unsigned short* __restrict__ featsT,
                                    const float4* __restrict__ xyzw,
                                    const float* __restrict__ new_xyz,
                                    int* __restrict__ idx) {
  __shared__ float tile[64][65];
  __shared__ int wl[4][64];
  __shared__ int wcnt[4];
  int bx = blockIdx.x;
  int t = threadIdx.x;
  if (bx < 4096) {
    const float r2 = (float)(0.08 * 0.08);
    int bm = bx;
    int lane = t & 63, w = t >> 6;
    int b = bm >> 10;
    float qx = new_xyz[bm * 3], qy = new_xyz[bm * 3 + 1], qz = new_xyz[bm * 3 + 2];
    float qq = __fadd_rn(__fadd_rn(__fmul_rn(qx, qx), __fmul_rn(qy, qy)), __fmul_rn(qz, qz));
    const float4* P = xyzw + (size_t)b * Nn + w * 4096;
    int cnt = 0;
    for (int n0 = 0; n0 < 4096; n0 += 64) {
      float4 p = P[n0 + lane];
      float dt = __fadd_rn(__fadd_rn(__fmul_rn(qx, p.x), __fmul_rn(qy, p.y)), __fmul_rn(qz, p.z));
      float d2 = __fsub_rn(__fadd_rn(qq, p.w), __fmul_rn(2.f, dt));
      bool valid = d2 < r2;
      unsigned long long mask = __ballot(valid);
      if (mask) {
        if (valid) {
          int pos = cnt + __popcll(mask & ((1ull << lane) - 1ull));
          if (pos < NSAMPLE) wl[w][pos] = w * 4096 + n0 + lane;
        }
        cnt += (int)__popcll(mask);
        if (cnt >= NSAMPLE) break;
      }
    }
    if (lane == 0) wcnt[w] = cnt;
    __syncthreads();
    if (t < NSAMPLE) {
      int c0 = wcnt[0], c1 = wcnt[1], c2 = wcnt[2], c3 = wcnt[3];
      int tot = c0 + c1 + c2 + c3;
      int cc = tot < NSAMPLE ? tot : NSAMPLE;
      int v;
      if (t < cc) {
        if (t < c0) v = wl[0][t];
        else if (t < c0 + c1) v = wl[1][t - c0];
        else if (t < c0 + c1 + c2) v = wl[2][t - c0 - c1];
        else v = wl[3][t - c0 - c1 - c2];
      } else {
        v = (c0 > 0) ? wl[0][0] : (c1 > 0) ? wl[1][0] : (c2 > 0) ? wl[2][0] : (c3 > 0) ? wl[3][0] : 0;
      }
      idx[(size_t)bm * NSAMPLE + t] = v;
    }
    return;
  }
  int fb = bx - 4096;             // 0..4095
  int b = fb >> 10;
  int rem = fb & 1023;
  int nt = rem >> 2, ct = rem & 3;
  int tx = t & 63, ty = t >> 6;
  const float* src = feats + ((size_t)b * Cc + ct * 64) * Nn + nt * 64;
#pragma unroll
  for (int i = 0; i < 16; i++) {
    int c = i * 4 + ty;
    tile[c][tx] = src[(size_t)c * Nn + tx];
  }
  __syncthreads();
  unsigned short* dst = featsT + ((size_t)b * Nn + nt * 64) * Cc + ct * 64;
  int c4 = (t & 15) * 4, n0 = t >> 4;
#pragma unroll
  for (int i = 0; i < 4; i++) {
    int n = i * 16 + n0;
    ushort4 v;
    v.x = f2bf(tile[c4][n]);
    v.y = f2bf(tile[c4 + 1][n]);
    v.z = f2bf(tile[c4 + 2][n]);
    v.w = f2bf(tile[c4 + 3][n]);
    *(ushort4*)&dst[(size_t)n * Cc + c4] = v;
  }
}

// ---------------- fused: R14 body verbatim; ONLY change = launch_bounds (256,3) ----------------
// (256,4) gave VGPR exactly 64 = zero W-prefetch headroom -> L2 latency exposed every kk
// (MfmaUtil 22%). (256,3) caps 170 total/wave: 64 AGPR + ~106 arch -> compiler can software-
// pipeline W loads across kk. Trade: 4->3 guaranteed waves/SIMD. Spill tripwire: FETCH ~52 MB.
__global__ __launch_bounds__(256, 3) void fused_kernel(
    const unsigned short* __restrict__ featsT, const float4* __restrict__ xyzw,
    const float* __restrict__ new_xyz, const int* __restrict__ idx,
    const unsigned short* __restrict__ W1b, const float* __restrict__ b1e,
    const unsigned short* __restrict__ W2b, const float* __restrict__ b2e,
    float* __restrict__ out) {
  __shared__ unsigned short Xf[64 * 256];  // 32768 B, swizzled feature tile / H tile
  __shared__ unsigned short Xco[64 * 40];  // 5120 B, coord K-chunk
  int t = threadIdx.x;
  int wave = t >> 6, lane = t & 63;
  int lr = lane & 15, kg = lane >> 4;
  int wcol = wave * 64;
  int bm = blockIdx.x;
  int b = bm >> 10;

  if (t < 64) {
    int ci = idx[(size_t)bm * NSAMPLE + t];
    float4 p = xyzw[(size_t)b * Nn + ci];
    unsigned int c01 = (unsigned int)f2bf(p.x - new_xyz[bm * 3])
                     | ((unsigned int)f2bf(p.y - new_xyz[bm * 3 + 1]) << 16);
    unsigned int c2 = (unsigned int)f2bf(p.z - new_xyz[bm * 3 + 2]);
    uint4 v0 = make_uint4(c01, c2, 0u, 0u);
    uint4 z = make_uint4(0u, 0u, 0u, 0u);
    uint4* row = (uint4*)&Xco[t * 40];
    row[0] = v0; row[1] = z; row[2] = z; row[3] = z; row[4] = z;
  }
  {
    int idxr = idx[(size_t)bm * NSAMPLE + wave * 16 + (lane & 15)];
#pragma unroll
    for (int i = 0; i < 8; i++) {
      int j = wave * 8 + i;                       // row pair 2j, 2j+1
      int iv = __shfl(idxr, 2 * i + (lane >> 5));
      int r7 = (2 * j + (lane >> 5)) & 7;
      int cg = (lane & 31) ^ r7;                  // swizzled global chunk (rule #21)
      gload_lds16(featsT + ((size_t)b * Nn + iv) * Cc + cg * 8, &Xf[j * 512]);
    }
  }
  __syncthreads();

  f32x4 acc[4][4];
#pragma unroll
  for (int mi = 0; mi < 4; mi++)
#pragma unroll
    for (int ni = 0; ni < 4; ni++) acc[mi][ni] = (f32x4){0.f, 0.f, 0.f, 0.f};
#pragma unroll
  for (int kk = 0; kk < 9; kk++) {
    bf16x8 w[4];
#pragma unroll
    for (int ni = 0; ni < 4; ni++)
      w[ni] = *(const bf16x8*)&W1b[(size_t)(wcol + ni * 16 + lr) * K1P + kk * 32 + kg * 8];
    bf16x8 a[4];
#pragma unroll
    for (int mi = 0; mi < 4; mi++) {
      int r = mi * 16 + lr;
      if (kk < 8) {
        int cs = ((kk * 4 + kg) ^ (r & 7)) * 8;
        a[mi] = *(const bf16x8*)&Xf[r * 256 + cs];
      } else {
        a[mi] = *(const bf16x8*)&Xco[r * 40 + kg * 8];
      }
    }
    __builtin_amdgcn_s_setprio(1);
#pragma unroll
    for (int mi = 0; mi < 4; mi++)
#pragma unroll
      for (int ni = 0; ni < 4; ni++)
        acc[mi][ni] = __builtin_amdgcn_mfma_f32_16x16x32_bf16(a[mi], w[ni], acc[mi][ni], 0, 0, 0);
    __builtin_amdgcn_s_setprio(0);
  }
  __syncthreads();  // B3

#pragma unroll
  for (int ni = 0; ni < 4; ni++) {
    int o = wcol + ni * 16 + lr;
    float bb = b1e[o];
#pragma unroll
    for (int mi = 0; mi < 4; mi++)
#pragma unroll
      for (int j = 0; j < 4; j++) {
        int r = mi * 16 + kg * 4 + j;
        float h = fmaxf(acc[mi][ni][j] + bb, 0.f);
        Xf[r * 256 + ((((o >> 3) ^ (r & 7)) << 3) + (o & 7))] = f2bf(h);
      }
  }
  __syncthreads();  // B4

#pragma unroll
  for (int mi = 0; mi < 4; mi++)
#pragma unroll
    for (int ni = 0; ni < 4; ni++) acc[mi][ni] = (f32x4){0.f, 0.f, 0.f, 0.f};
#pragma unroll
  for (int kk = 0; kk < 8; kk++) {
    bf16x8 w[4];
#pragma unroll
    for (int ni = 0; ni < 4; ni++)
      w[ni] = *(const bf16x8*)&W2b[(size_t)(wcol + ni * 16 + lr) * 256 + kk * 32 + kg * 8];
    bf16x8 a[4];
#pragma unroll
    for (int mi = 0; mi < 4; mi++) {
      int r = mi * 16 + lr;
      int cs = ((kk * 4 + kg) ^ (r & 7)) * 8;
      a[mi] = *(const bf16x8*)&Xf[r * 256 + cs];
    }
    __builtin_amdgcn_s_setprio(1);
#pragma unroll
    for (int mi = 0; mi < 4; mi++)
#pragma unroll
      for (int ni = 0; ni < 4; ni++)
        acc[mi][ni] = __builtin_amdgcn_mfma_f32_16x16x32_bf16(a[mi], w[ni], acc[mi][ni], 0, 0, 0);
    __builtin_amdgcn_s_setprio(0);
  }
  {
    int m = bm & (Mm - 1);
#pragma unroll
    for (int ni = 0; ni < 4; ni++) {
      float bv = b2e[wcol + ni * 16 + lr];
      float v = 0.f;  // relu(max) == max(relu)
#pragma unroll
      for (int mi = 0; mi < 4; mi++)
#pragma unroll
        for (int j = 0; j < 4; j++) v = fmaxf(v, acc[mi][ni][j] + bv);
      v = fmaxf(v, __shfl_xor(v, 16));
      v = fmaxf(v, __shfl_xor(v, 32));
      if (kg == 0)
        out[((size_t)b * 256 + wcol + ni * 16 + lr) * Mm + m] = v;
    }
  }
}

extern "C" void kernel_launch(void* const* d_in, const int* in_sizes, int n_in,
                              void* d_out, int out_size, void* d_ws, size_t ws_size,
                              hipStream_t stream) {
  (void)in_sizes; (void)n_in; (void)out_size; (void)ws_size;
  const float* xyz     = (const float*)d_in[0];
  const float* new_xyz = (const float*)d_in[1];
  const float* feats   = (const float*)d_in[2];
  const float* W1 = (const float*)d_in[3];
  const float* b1 = (const float*)d_in[4];
  const float* g1 = (const float*)d_in[5];
  const float* be1 = (const float*)d_in[6];
  const float* m1 = (const float*)d_in[7];
  const float* v1 = (const float*)d_in[8];
  const float* W2 = (const float*)d_in[9];
  const float* b2 = (const float*)d_in[10];
  const float* g2 = (const float*)d_in[11];
  const float* be2 = (const float*)d_in[12];
  const float* m2 = (const float*)d_in[13];
  const float* v2 = (const float*)d_in[14];
  float* out = (float*)d_out;

  char* ws = (char*)d_ws;
  unsigned short* W1b   = (unsigned short*)(ws + 0);         // 147456 B ([256][288])
  unsigned short* W2b   = (unsigned short*)(ws + 147456);    // 131072 B
  float*          b1e   = (float*)(ws + 278528);             // 1024 B
  float*          b2e   = (float*)(ws + 279552);             // 1024 B
  float4*         xyzw  = (float4*)(ws + 280576);            // 1048576 B
  unsigned short* featsT= (unsigned short*)(ws + 1329152);   // 33554432 B
  int*            idx   = (int*)(ws + 34883584);             // 1048576 B

  prep_xyzw_kernel<<<288 + 256, 256, 0, stream>>>(
      W1, b1, g1, be1, m1, v1, W2, b2, g2, be2, m2, v2, xyz, W1b, b1e, W2b, b2e, xyzw);
  featsT_ballq_kernel<<<4096 + 4096, 256, 0, stream>>>(feats, featsT, xyzw, new_xyz, idx);
  fused_kernel<<<Bb * Mm, 256, 0, stream>>>(featsT, xyzw, new_xyz, idx,
                                            W1b, b1e, W2b, b2e, out);
}

// Round 17
// 175.406 us; speedup vs baseline: 1.0621x; 1.0490x over previous
//
#include <hip/hip_runtime.h>
#include <stdint.h>

typedef __bf16 bf16x8 __attribute__((ext_vector_type(8)));
typedef float f32x4 __attribute__((ext_vector_type(4)));

#define NSAMPLE 64
static constexpr int Bb = 4, Nn = 16384, Mm = 1024, Cc = 256;
static constexpr int K1P = 288;   // layer-1 K: 256 features + 3 coords + pad (9 x 32)

__device__ __forceinline__ unsigned short f2bf(float f) {
  unsigned int u = __builtin_bit_cast(unsigned int, f);
  u = u + 0x7fffu + ((u >> 16) & 1u);
  return (unsigned short)(u >> 16);
}

// async global->LDS, 16B per lane; LDS dest = wave-uniform base + lane*16
__device__ __forceinline__ void gload_lds16(const void* g, void* lds) {
  __builtin_amdgcn_global_load_lds(
      (const __attribute__((address_space(1))) uint32_t*)g,
      (__attribute__((address_space(3))) uint32_t*)lds, 16, 0, 0);
}

// ---- prep + xyzw merged at BLOCK level (R14 verbatim): blocks 0..287 prep, 288..543 xyzw ----
__global__ void prep_xyzw_kernel(const float* __restrict__ W1, const float* __restrict__ b1,
                                 const float* __restrict__ g1, const float* __restrict__ be1,
                                 const float* __restrict__ m1, const float* __restrict__ v1,
                                 const float* __restrict__ W2, const float* __restrict__ b2,
                                 const float* __restrict__ g2, const float* __restrict__ be2,
                                 const float* __restrict__ m2, const float* __restrict__ v2,
                                 const float* __restrict__ xyz,
                                 unsigned short* __restrict__ W1b, float* __restrict__ b1e,
                                 unsigned short* __restrict__ W2b, float* __restrict__ b2e,
                                 float4* __restrict__ xyzw) {
  int bx = blockIdx.x;
  if (bx < 288) {
    int t = bx * 256 + threadIdx.x;
    if (t < 256 * K1P) {
      int o = t / K1P, k = t - o * K1P;
      float s = g1[o] / sqrtf(v1[o] + 1e-5f);
      float w = 0.f;
      if (k < 256) w = W1[o * 259 + 3 + k];
      else if (k < 259) w = W1[o * 259 + (k - 256)];
      W1b[t] = f2bf(w * s);
    }
    if (t < 256 * 256) {
      int o = t >> 8;
      float s = g2[o] / sqrtf(v2[o] + 1e-5f);
      W2b[t] = f2bf(W2[t] * s);
    }
    if (t < 256) {
      float s1 = g1[t] / sqrtf(v1[t] + 1e-5f);
      b1e[t] = s1 * (b1[t] - m1[t]) + be1[t];
      float s2 = g2[t] / sqrtf(v2[t] + 1e-5f);
      b2e[t] = s2 * (b2[t] - m2[t]) + be2[t];
    }
    return;
  }
  int t = (bx - 288) * 256 + threadIdx.x;  // 0..65535
  float x = xyz[t * 3], y = xyz[t * 3 + 1], z = xyz[t * 3 + 2];
  float pp = __fadd_rn(__fadd_rn(__fmul_rn(x, x), __fmul_rn(y, y)), __fmul_rn(z, z));
  xyzw[t] = make_float4(x, y, z, pp);
}

// ---- featsT + ballq merged at BLOCK level (R14 verbatim) ----
__global__ void featsT_ballq_kernel(const float* __restrict__ feats,
                                    unsigned short* __restrict__ featsT,
                                    const float4* __restrict__ xyzw,
                                    const float* __restrict__ new_xyz,
                                    int* __restrict__ idx) {
  __shared__ float tile[64][65];
  __shared__ int wl[4][64];
  __shared__ int wcnt[4];
  int bx = blockIdx.x;
  int t = threadIdx.x;
  if (bx < 4096) {
    const float r2 = (float)(0.08 * 0.08);
    int bm = bx;
    int lane = t & 63, w = t >> 6;
    int b = bm >> 10;
    float qx = new_xyz[bm * 3], qy = new_xyz[bm * 3 + 1], qz = new_xyz[bm * 3 + 2];
    float qq = __fadd_rn(__fadd_rn(__fmul_rn(qx, qx), __fmul_rn(qy, qy)), __fmul_rn(qz, qz));
    const float4* P = xyzw + (size_t)b * Nn + w * 4096;
    int cnt = 0;
    for (int n0 = 0; n0 < 4096; n0 += 64) {
      float4 p = P[n0 + lane];
      float dt = __fadd_rn(__fadd_rn(__fmul_rn(qx, p.x), __fmul_rn(qy, p.y)), __fmul_rn(qz, p.z));
      float d2 = __fsub_rn(__fadd_rn(qq, p.w), __fmul_rn(2.f, dt));
      bool valid = d2 < r2;
      unsigned long long mask = __ballot(valid);
      if (mask) {
        if (valid) {
          int pos = cnt + __popcll(mask & ((1ull << lane) - 1ull));
          if (pos < NSAMPLE) wl[w][pos] = w * 4096 + n0 + lane;
        }
        cnt += (int)__popcll(mask);
        if (cnt >= NSAMPLE) break;
      }
    }
    if (lane == 0) wcnt[w] = cnt;
    __syncthreads();
    if (t < NSAMPLE) {
      int c0 = wcnt[0], c1 = wcnt[1], c2 = wcnt[2], c3 = wcnt[3];
      int tot = c0 + c1 + c2 + c3;
      int cc = tot < NSAMPLE ? tot : NSAMPLE;
      int v;
      if (t < cc) {
        if (t < c0) v = wl[0][t];
        else if (t < c0 + c1) v = wl[1][t - c0];
        else if (t < c0 + c1 + c2) v = wl[2][t - c0 - c1];
        else v = wl[3][t - c0 - c1 - c2];
      } else {
        v = (c0 > 0) ? wl[0][0] : (c1 > 0) ? wl[1][0] : (c2 > 0) ? wl[2][0] : (c3 > 0) ? wl[3][0] : 0;
      }
      idx[(size_t)bm * NSAMPLE + t] = v;
    }
    return;
  }
  int fb = bx - 4096;             // 0..4095
  int b = fb >> 10;
  int rem = fb & 1023;
  int nt = rem >> 2, ct = rem & 3;
  int tx = t & 63, ty = t >> 6;
  const float* src = feats + ((size_t)b * Cc + ct * 64) * Nn + nt * 64;
#pragma unroll
  for (int i = 0; i < 16; i++) {
    int c = i * 4 + ty;
    tile[c][tx] = src[(size_t)c * Nn + tx];
  }
  __syncthreads();
  unsigned short* dst = featsT + ((size_t)b * Nn + nt * 64) * Cc + ct * 64;
  int c4 = (t & 15) * 4, n0 = t >> 4;
#pragma unroll
  for (int i = 0; i < 4; i++) {
    int n = i * 16 + n0;
    ushort4 v;
    v.x = f2bf(tile[c4][n]);
    v.y = f2bf(tile[c4 + 1][n]);
    v.z = f2bf(tile[c4 + 2][n]);
    v.w = f2bf(tile[c4 + 3][n]);
    *(ushort4*)&dst[(size_t)n * Cc + c4] = v;
  }
}

// ---------------- fused: R14 body + hand double-buffered W prefetch, (256,4) -------------------
// kk loops fully unrolled; W held in w[2][4] (static index) and kk+1's 4 loads are issued BEFORE
// kk's 16 MFMAs -> vmcnt wait for w[cur] lands after ~310 cyc of prior-kk MFMA, hiding the ~200
// cyc L2 latency that was exposed every kk at 64 arch regs. Budget: 32 W + 16 A + ~16 addr = 64
// arch + 64 AGPR = 128 = (256,4) cap. Spill tripwire: FETCH must stay ~35-55 MB.
__global__ __launch_bounds__(256, 4) void fused_kernel(
    const unsigned short* __restrict__ featsT, const float4* __restrict__ xyzw,
    const float* __restrict__ new_xyz, const int* __restrict__ idx,
    const unsigned short* __restrict__ W1b, const float* __restrict__ b1e,
    const unsigned short* __restrict__ W2b, const float* __restrict__ b2e,
    float* __restrict__ out) {
  __shared__ unsigned short Xf[64 * 256];  // 32768 B, swizzled feature tile / H tile
  __shared__ unsigned short Xco[64 * 40];  // 5120 B, coord K-chunk
  int t = threadIdx.x;
  int wave = t >> 6, lane = t & 63;
  int lr = lane & 15, kg = lane >> 4;
  int wcol = wave * 64;
  int bm = blockIdx.x;
  int b = bm >> 10;

  if (t < 64) {
    int ci = idx[(size_t)bm * NSAMPLE + t];
    float4 p = xyzw[(size_t)b * Nn + ci];
    unsigned int c01 = (unsigned int)f2bf(p.x - new_xyz[bm * 3])
                     | ((unsigned int)f2bf(p.y - new_xyz[bm * 3 + 1]) << 16);
    unsigned int c2 = (unsigned int)f2bf(p.z - new_xyz[bm * 3 + 2]);
    uint4 v0 = make_uint4(c01, c2, 0u, 0u);
    uint4 z = make_uint4(0u, 0u, 0u, 0u);
    uint4* row = (uint4*)&Xco[t * 40];
    row[0] = v0; row[1] = z; row[2] = z; row[3] = z; row[4] = z;
  }
  {
    int idxr = idx[(size_t)bm * NSAMPLE + wave * 16 + (lane & 15)];
#pragma unroll
    for (int i = 0; i < 8; i++) {
      int j = wave * 8 + i;                       // row pair 2j, 2j+1
      int iv = __shfl(idxr, 2 * i + (lane >> 5));
      int r7 = (2 * j + (lane >> 5)) & 7;
      int cg = (lane & 31) ^ r7;                  // swizzled global chunk (rule #21)
      gload_lds16(featsT + ((size_t)b * Nn + iv) * Cc + cg * 8, &Xf[j * 512]);
    }
  }
  __syncthreads();

  // ---- layer 1: [64x288]x[288x256]; kk 0..7 from Xf (swizzled), kk 8 from Xco ----
  f32x4 acc[4][4];
#pragma unroll
  for (int mi = 0; mi < 4; mi++)
#pragma unroll
    for (int ni = 0; ni < 4; ni++) acc[mi][ni] = (f32x4){0.f, 0.f, 0.f, 0.f};
  {
    bf16x8 w[2][4];
#pragma unroll
    for (int ni = 0; ni < 4; ni++)
      w[0][ni] = *(const bf16x8*)&W1b[(size_t)(wcol + ni * 16 + lr) * K1P + kg * 8];
#pragma unroll
    for (int kk = 0; kk < 9; kk++) {
      int cur = kk & 1, nxt = cur ^ 1;
      if (kk < 8) {
#pragma unroll
        for (int ni = 0; ni < 4; ni++)
          w[nxt][ni] =
              *(const bf16x8*)&W1b[(size_t)(wcol + ni * 16 + lr) * K1P + (kk + 1) * 32 + kg * 8];
      }
      bf16x8 a[4];
#pragma unroll
      for (int mi = 0; mi < 4; mi++) {
        int r = mi * 16 + lr;
        if (kk < 8) {
          int cs = ((kk * 4 + kg) ^ (r & 7)) * 8;
          a[mi] = *(const bf16x8*)&Xf[r * 256 + cs];
        } else {
          a[mi] = *(const bf16x8*)&Xco[r * 40 + kg * 8];
        }
      }
      __builtin_amdgcn_s_setprio(1);
#pragma unroll
      for (int mi = 0; mi < 4; mi++)
#pragma unroll
        for (int ni = 0; ni < 4; ni++)
          acc[mi][ni] =
              __builtin_amdgcn_mfma_f32_16x16x32_bf16(a[mi], w[cur][ni], acc[mi][ni], 0, 0, 0);
      __builtin_amdgcn_s_setprio(0);
    }
  }
  __syncthreads();  // B3

#pragma unroll
  for (int ni = 0; ni < 4; ni++) {
    int o = wcol + ni * 16 + lr;
    float bb = b1e[o];
#pragma unroll
    for (int mi = 0; mi < 4; mi++)
#pragma unroll
      for (int j = 0; j < 4; j++) {
        int r = mi * 16 + kg * 4 + j;
        float h = fmaxf(acc[mi][ni][j] + bb, 0.f);
        Xf[r * 256 + ((((o >> 3) ^ (r & 7)) << 3) + (o & 7))] = f2bf(h);
      }
  }
  __syncthreads();  // B4

  // ---- layer 2: [64x256]x[256x256] from H (same swizzle), same W double-buffer ----
#pragma unroll
  for (int mi = 0; mi < 4; mi++)
#pragma unroll
    for (int ni = 0; ni < 4; ni++) acc[mi][ni] = (f32x4){0.f, 0.f, 0.f, 0.f};
  {
    bf16x8 w[2][4];
#pragma unroll
    for (int ni = 0; ni < 4; ni++)
      w[0][ni] = *(const bf16x8*)&W2b[(size_t)(wcol + ni * 16 + lr) * 256 + kg * 8];
#pragma unroll
    for (int kk = 0; kk < 8; kk++) {
      int cur = kk & 1, nxt = cur ^ 1;
      if (kk < 7) {
#pragma unroll
        for (int ni = 0; ni < 4; ni++)
          w[nxt][ni] =
              *(const bf16x8*)&W2b[(size_t)(wcol + ni * 16 + lr) * 256 + (kk + 1) * 32 + kg * 8];
      }
      bf16x8 a[4];
#pragma unroll
      for (int mi = 0; mi < 4; mi++) {
        int r = mi * 16 + lr;
        int cs = ((kk * 4 + kg) ^ (r & 7)) * 8;
        a[mi] = *(const bf16x8*)&Xf[r * 256 + cs];
      }
      __builtin_amdgcn_s_setprio(1);
#pragma unroll
      for (int mi = 0; mi < 4; mi++)
#pragma unroll
        for (int ni = 0; ni < 4; ni++)
          acc[mi][ni] =
              __builtin_amdgcn_mfma_f32_16x16x32_bf16(a[mi], w[cur][ni], acc[mi][ni], 0, 0, 0);
      __builtin_amdgcn_s_setprio(0);
    }
  }
  {
    int m = bm & (Mm - 1);
#pragma unroll
    for (int ni = 0; ni < 4; ni++) {
      float bv = b2e[wcol + ni * 16 + lr];
      float v = 0.f;  // relu(max) == max(relu)
#pragma unroll
      for (int mi = 0; mi < 4; mi++)
#pragma unroll
        for (int j = 0; j < 4; j++) v = fmaxf(v, acc[mi][ni][j] + bv);
      v = fmaxf(v, __shfl_xor(v, 16));
      v = fmaxf(v, __shfl_xor(v, 32));
      if (kg == 0)
        out[((size_t)b * 256 + wcol + ni * 16 + lr) * Mm + m] = v;
    }
  }
}

extern "C" void kernel_launch(void* const* d_in, const int* in_sizes, int n_in,
                              void* d_out, int out_size, void* d_ws, size_t ws_size,
                              hipStream_t stream) {
  (void)in_sizes; (void)n_in; (void)out_size; (void)ws_size;
  const float* xyz     = (const float*)d_in[0];
  const float* new_xyz = (const float*)d_in[1];
  const float* feats   = (const float*)d_in[2];
  const float* W1 = (const float*)d_in[3];
  const float* b1 = (const float*)d_in[4];
  const float* g1 = (const float*)d_in[5];
  const float* be1 = (const float*)d_in[6];
  const float* m1 = (const float*)d_in[7];
  const float* v1 = (const float*)d_in[8];
  const float* W2 = (const float*)d_in[9];
  const float* b2 = (const float*)d_in[10];
  const float* g2 = (const float*)d_in[11];
  const float* be2 = (const float*)d_in[12];
  const float* m2 = (const float*)d_in[13];
  const float* v2 = (const float*)d_in[14];
  float* out = (float*)d_out;

  char* ws = (char*)d_ws;
  unsigned short* W1b   = (unsigned short*)(ws + 0);         // 147456 B ([256][288])
  unsigned short* W2b   = (unsigned short*)(ws + 147456);    // 131072 B
  float*          b1e   = (float*)(ws + 278528);             // 1024 B
  float*          b2e   = (float*)(ws + 279552);             // 1024 B
  float4*         xyzw  = (float4*)(ws + 280576);            // 1048576 B
  unsigned short* featsT= (unsigned short*)(ws + 1329152);   // 33554432 B
  int*            idx   = (int*)(ws + 34883584);             // 1048576 B

  prep_xyzw_kernel<<<288 + 256, 256, 0, stream>>>(
      W1, b1, g1, be1, m1, v1, W2, b2, g2, be2, m2, v2, xyz, W1b, b1e, W2b, b2e, xyzw);
  featsT_ballq_kernel<<<4096 + 4096, 256, 0, stream>>>(feats, featsT, xyzw, new_xyz, idx);
  fused_kernel<<<Bb * Mm, 256, 0, stream>>>(featsT, xyzw, new_xyz, idx,
                                            W1b, b1e, W2b, b2e, out);
}

// Round 18
// 173.360 us; speedup vs baseline: 1.0747x; 1.0118x over previous
//
#include <hip/hip_runtime.h>
#include <stdint.h>

typedef __bf16 bf16x8 __attribute__((ext_vector_type(8)));
typedef float f32x4 __attribute__((ext_vector_type(4)));

#define NSAMPLE 64
static constexpr int Bb = 4, Nn = 16384, Mm = 1024, Cc = 256;
static constexpr int K1P = 288;   // layer-1 K: 256 features + 3 coords + pad (9 x 32)

__device__ __forceinline__ unsigned short f2bf(float f) {
  unsigned int u = __builtin_bit_cast(unsigned int, f);
  u = u + 0x7fffu + ((u >> 16) & 1u);
  return (unsigned short)(u >> 16);
}

// async global->LDS, 16B per lane; LDS dest = wave-uniform base + lane*16
__device__ __forceinline__ void gload_lds16(const void* g, void* lds) {
  __builtin_amdgcn_global_load_lds(
      (const __attribute__((address_space(1))) uint32_t*)g,
      (__attribute__((address_space(3))) uint32_t*)lds, 16, 0, 0);
}

// ---- ALL helpers in ONE kernel, block-range partitioned (mutually independent work):
// blocks 0..4095: ballq split-scan from RAW xyz (|p|^2 computed inline with the exact same
//   __fmul_rn/__fadd_rn op order the old xyzw_kernel used -> bit-identical d2);
// blocks 4096..8191: featsT (R8-verbatim);
// blocks 8192..8479: prep (R1-verbatim).
// ballq first: it's the latency-bound pole; overlaps with BW-bound featsT (R13-proven pattern).
__global__ void helpers_kernel(const float* __restrict__ xyz,
                               const float* __restrict__ new_xyz,
                               const float* __restrict__ feats,
                               const float* __restrict__ W1, const float* __restrict__ b1,
                               const float* __restrict__ g1, const float* __restrict__ be1,
                               const float* __restrict__ m1, const float* __restrict__ v1,
                               const float* __restrict__ W2, const float* __restrict__ b2,
                               const float* __restrict__ g2, const float* __restrict__ be2,
                               const float* __restrict__ m2, const float* __restrict__ v2,
                               unsigned short* __restrict__ W1b, float* __restrict__ b1e,
                               unsigned short* __restrict__ W2b, float* __restrict__ b2e,
                               unsigned short* __restrict__ featsT,
                               int* __restrict__ idx) {
  __shared__ float tile[64][65];
  __shared__ int wl[4][64];
  __shared__ int wcnt[4];
  int bx = blockIdx.x;
  int t = threadIdx.x;
  if (bx < 4096) {
    // ---------------- ballq: split-scan over raw xyz ----------------
    const float r2 = (float)(0.08 * 0.08);
    int bm = bx;
    int lane = t & 63, w = t >> 6;
    int b = bm >> 10;
    float qx = new_xyz[bm * 3], qy = new_xyz[bm * 3 + 1], qz = new_xyz[bm * 3 + 2];
    float qq = __fadd_rn(__fadd_rn(__fmul_rn(qx, qx), __fmul_rn(qy, qy)), __fmul_rn(qz, qz));
    const float* P = xyz + ((size_t)b * Nn + w * 4096) * 3;
    int cnt = 0;
    for (int n0 = 0; n0 < 4096; n0 += 64) {
      const float* pp = P + (n0 + lane) * 3;
      float x = pp[0], y = pp[1], z = pp[2];
      float p2 = __fadd_rn(__fadd_rn(__fmul_rn(x, x), __fmul_rn(y, y)), __fmul_rn(z, z));
      float dt = __fadd_rn(__fadd_rn(__fmul_rn(qx, x), __fmul_rn(qy, y)), __fmul_rn(qz, z));
      float d2 = __fsub_rn(__fadd_rn(qq, p2), __fmul_rn(2.f, dt));
      bool valid = d2 < r2;
      unsigned long long mask = __ballot(valid);
      if (mask) {
        if (valid) {
          int pos = cnt + __popcll(mask & ((1ull << lane) - 1ull));
          if (pos < NSAMPLE) wl[w][pos] = w * 4096 + n0 + lane;
        }
        cnt += (int)__popcll(mask);
        if (cnt >= NSAMPLE) break;
      }
    }
    if (lane == 0) wcnt[w] = cnt;
    __syncthreads();
    if (t < NSAMPLE) {
      int c0 = wcnt[0], c1 = wcnt[1], c2 = wcnt[2], c3 = wcnt[3];
      int tot = c0 + c1 + c2 + c3;
      int cc = tot < NSAMPLE ? tot : NSAMPLE;
      int v;
      if (t < cc) {
        if (t < c0) v = wl[0][t];
        else if (t < c0 + c1) v = wl[1][t - c0];
        else if (t < c0 + c1 + c2) v = wl[2][t - c0 - c1];
        else v = wl[3][t - c0 - c1 - c2];
      } else {
        v = (c0 > 0) ? wl[0][0] : (c1 > 0) ? wl[1][0] : (c2 > 0) ? wl[2][0] : (c3 > 0) ? wl[3][0] : 0;
      }
      idx[(size_t)bm * NSAMPLE + t] = v;
    }
    return;
  }
  if (bx < 8192) {
    // ---------------- featsT — R8 verbatim body ----------------
    int fb = bx - 4096;             // 0..4095
    int b = fb >> 10;
    int rem = fb & 1023;
    int nt = rem >> 2, ct = rem & 3;
    int tx = t & 63, ty = t >> 6;
    const float* src = feats + ((size_t)b * Cc + ct * 64) * Nn + nt * 64;
#pragma unroll
    for (int i = 0; i < 16; i++) {
      int c = i * 4 + ty;
      tile[c][tx] = src[(size_t)c * Nn + tx];
    }
    __syncthreads();
    unsigned short* dst = featsT + ((size_t)b * Nn + nt * 64) * Cc + ct * 64;
    int c4 = (t & 15) * 4, n0 = t >> 4;
#pragma unroll
    for (int i = 0; i < 4; i++) {
      int n = i * 16 + n0;
      ushort4 v;
      v.x = f2bf(tile[c4][n]);
      v.y = f2bf(tile[c4 + 1][n]);
      v.z = f2bf(tile[c4 + 2][n]);
      v.w = f2bf(tile[c4 + 3][n]);
      *(ushort4*)&dst[(size_t)n * Cc + c4] = v;
    }
    return;
  }
  // ---------------- prep body (R1 verbatim, t from local block range) ----------------
  int g = (bx - 8192) * 256 + t;
  if (g < 256 * K1P) {
    int o = g / K1P, k = g - o * K1P;
    float s = g1[o] / sqrtf(v1[o] + 1e-5f);
    float w = 0.f;
    if (k < 256) w = W1[o * 259 + 3 + k];
    else if (k < 259) w = W1[o * 259 + (k - 256)];
    W1b[g] = f2bf(w * s);
  }
  if (g < 256 * 256) {
    int o = g >> 8;
    float s = g2[o] / sqrtf(v2[o] + 1e-5f);
    W2b[g] = f2bf(W2[g] * s);
  }
  if (g < 256) {
    float s1 = g1[g] / sqrtf(v1[g] + 1e-5f);
    b1e[g] = s1 * (b1[g] - m1[g]) + be1[g];
    float s2 = g2[g] / sqrtf(v2[g] + 1e-5f);
    b2e[g] = s2 * (b2[g] - m2[g]) + be2[g];
  }
}

// ---------------- fused: R17 body verbatim; Xco coords read straight from raw xyz --------------
__global__ __launch_bounds__(256, 4) void fused_kernel(
    const unsigned short* __restrict__ featsT, const float* __restrict__ xyz,
    const float* __restrict__ new_xyz, const int* __restrict__ idx,
    const unsigned short* __restrict__ W1b, const float* __restrict__ b1e,
    const unsigned short* __restrict__ W2b, const float* __restrict__ b2e,
    float* __restrict__ out) {
  __shared__ unsigned short Xf[64 * 256];  // 32768 B, swizzled feature tile / H tile
  __shared__ unsigned short Xco[64 * 40];  // 5120 B, coord K-chunk
  int t = threadIdx.x;
  int wave = t >> 6, lane = t & 63;
  int lr = lane & 15, kg = lane >> 4;
  int wcol = wave * 64;
  int bm = blockIdx.x;
  int b = bm >> 10;

  if (t < 64) {
    int ci = idx[(size_t)bm * NSAMPLE + t];
    const float* pp = xyz + ((size_t)b * Nn + ci) * 3;
    float px = pp[0], py = pp[1], pz = pp[2];
    unsigned int c01 = (unsigned int)f2bf(px - new_xyz[bm * 3])
                     | ((unsigned int)f2bf(py - new_xyz[bm * 3 + 1]) << 16);
    unsigned int c2 = (unsigned int)f2bf(pz - new_xyz[bm * 3 + 2]);
    uint4 v0 = make_uint4(c01, c2, 0u, 0u);
    uint4 z = make_uint4(0u, 0u, 0u, 0u);
    uint4* row = (uint4*)&Xco[t * 40];
    row[0] = v0; row[1] = z; row[2] = z; row[3] = z; row[4] = z;
  }
  {
    int idxr = idx[(size_t)bm * NSAMPLE + wave * 16 + (lane & 15)];
#pragma unroll
    for (int i = 0; i < 8; i++) {
      int j = wave * 8 + i;                       // row pair 2j, 2j+1
      int iv = __shfl(idxr, 2 * i + (lane >> 5));
      int r7 = (2 * j + (lane >> 5)) & 7;
      int cg = (lane & 31) ^ r7;                  // swizzled global chunk (rule #21)
      gload_lds16(featsT + ((size_t)b * Nn + iv) * Cc + cg * 8, &Xf[j * 512]);
    }
  }
  __syncthreads();

  // ---- layer 1: [64x288]x[288x256]; kk 0..7 from Xf (swizzled), kk 8 from Xco ----
  f32x4 acc[4][4];
#pragma unroll
  for (int mi = 0; mi < 4; mi++)
#pragma unroll
    for (int ni = 0; ni < 4; ni++) acc[mi][ni] = (f32x4){0.f, 0.f, 0.f, 0.f};
  {
    bf16x8 w[2][4];
#pragma unroll
    for (int ni = 0; ni < 4; ni++)
      w[0][ni] = *(const bf16x8*)&W1b[(size_t)(wcol + ni * 16 + lr) * K1P + kg * 8];
#pragma unroll
    for (int kk = 0; kk < 9; kk++) {
      int cur = kk & 1, nxt = cur ^ 1;
      if (kk < 8) {
#pragma unroll
        for (int ni = 0; ni < 4; ni++)
          w[nxt][ni] =
              *(const bf16x8*)&W1b[(size_t)(wcol + ni * 16 + lr) * K1P + (kk + 1) * 32 + kg * 8];
      }
      bf16x8 a[4];
#pragma unroll
      for (int mi = 0; mi < 4; mi++) {
        int r = mi * 16 + lr;
        if (kk < 8) {
          int cs = ((kk * 4 + kg) ^ (r & 7)) * 8;
          a[mi] = *(const bf16x8*)&Xf[r * 256 + cs];
        } else {
          a[mi] = *(const bf16x8*)&Xco[r * 40 + kg * 8];
        }
      }
      __builtin_amdgcn_s_setprio(1);
#pragma unroll
      for (int mi = 0; mi < 4; mi++)
#pragma unroll
        for (int ni = 0; ni < 4; ni++)
          acc[mi][ni] =
              __builtin_amdgcn_mfma_f32_16x16x32_bf16(a[mi], w[cur][ni], acc[mi][ni], 0, 0, 0);
      __builtin_amdgcn_s_setprio(0);
    }
  }
  __syncthreads();  // B3

#pragma unroll
  for (int ni = 0; ni < 4; ni++) {
    int o = wcol + ni * 16 + lr;
    float bb = b1e[o];
#pragma unroll
    for (int mi = 0; mi < 4; mi++)
#pragma unroll
      for (int j = 0; j < 4; j++) {
        int r = mi * 16 + kg * 4 + j;
        float h = fmaxf(acc[mi][ni][j] + bb, 0.f);
        Xf[r * 256 + ((((o >> 3) ^ (r & 7)) << 3) + (o & 7))] = f2bf(h);
      }
  }
  __syncthreads();  // B4

  // ---- layer 2: [64x256]x[256x256] from H (same swizzle), same W double-buffer ----
#pragma unroll
  for (int mi = 0; mi < 4; mi++)
#pragma unroll
    for (int ni = 0; ni < 4; ni++) acc[mi][ni] = (f32x4){0.f, 0.f, 0.f, 0.f};
  {
    bf16x8 w[2][4];
#pragma unroll
    for (int ni = 0; ni < 4; ni++)
      w[0][ni] = *(const bf16x8*)&W2b[(size_t)(wcol + ni * 16 + lr) * 256 + kg * 8];
#pragma unroll
    for (int kk = 0; kk < 8; kk++) {
      int cur = kk & 1, nxt = cur ^ 1;
      if (kk < 7) {
#pragma unroll
        for (int ni = 0; ni < 4; ni++)
          w[nxt][ni] =
              *(const bf16x8*)&W2b[(size_t)(wcol + ni * 16 + lr) * 256 + (kk + 1) * 32 + kg * 8];
      }
      bf16x8 a[4];
#pragma unroll
      for (int mi = 0; mi < 4; mi++) {
        int r = mi * 16 + lr;
        int cs = ((kk * 4 + kg) ^ (r & 7)) * 8;
        a[mi] = *(const bf16x8*)&Xf[r * 256 + cs];
      }
      __builtin_amdgcn_s_setprio(1);
#pragma unroll
      for (int mi = 0; mi < 4; mi++)
#pragma unroll
        for (int ni = 0; ni < 4; ni++)
          acc[mi][ni] =
              __builtin_amdgcn_mfma_f32_16x16x32_bf16(a[mi], w[cur][ni], acc[mi][ni], 0, 0, 0);
      __builtin_amdgcn_s_setprio(0);
    }
  }
  {
    int m = bm & (Mm - 1);
#pragma unroll
    for (int ni = 0; ni < 4; ni++) {
      float bv = b2e[wcol + ni * 16 + lr];
      float v = 0.f;  // relu(max) == max(relu)
#pragma unroll
      for (int mi = 0; mi < 4; mi++)
#pragma unroll
        for (int j = 0; j < 4; j++) v = fmaxf(v, acc[mi][ni][j] + bv);
      v = fmaxf(v, __shfl_xor(v, 16));
      v = fmaxf(v, __shfl_xor(v, 32));
      if (kg == 0)
        out[((size_t)b * 256 + wcol + ni * 16 + lr) * Mm + m] = v;
    }
  }
}

extern "C" void kernel_launch(void* const* d_in, const int* in_sizes, int n_in,
                              void* d_out, int out_size, void* d_ws, size_t ws_size,
                              hipStream_t stream) {
  (void)in_sizes; (void)n_in; (void)out_size; (void)ws_size;
  const float* xyz     = (const float*)d_in[0];
  const float* new_xyz = (const float*)d_in[1];
  const float* feats   = (const float*)d_in[2];
  const float* W1 = (const float*)d_in[3];
  const float* b1 = (const float*)d_in[4];
  const float* g1 = (const float*)d_in[5];
  const float* be1 = (const float*)d_in[6];
  const float* m1 = (const float*)d_in[7];
  const float* v1 = (const float*)d_in[8];
  const float* W2 = (const float*)d_in[9];
  const float* b2 = (const float*)d_in[10];
  const float* g2 = (const float*)d_in[11];
  const float* be2 = (const float*)d_in[12];
  const float* m2 = (const float*)d_in[13];
  const float* v2 = (const float*)d_in[14];
  float* out = (float*)d_out;

  char* ws = (char*)d_ws;
  unsigned short* W1b   = (unsigned short*)(ws + 0);         // 147456 B ([256][288])
  unsigned short* W2b   = (unsigned short*)(ws + 147456);    // 131072 B
  float*          b1e   = (float*)(ws + 278528);             // 1024 B
  float*          b2e   = (float*)(ws + 279552);             // 1024 B
  unsigned short* featsT= (unsigned short*)(ws + 280576);    // 33554432 B
  int*            idx   = (int*)(ws + 33835008);             // 1048576 B (end ~34.9 MB)

  helpers_kernel<<<4096 + 4096 + 288, 256, 0, stream>>>(
      xyz, new_xyz, feats, W1, b1, g1, be1, m1, v1, W2, b2, g2, be2, m2, v2,
      W1b, b1e, W2b, b2e, featsT, idx);
  fused_kernel<<<Bb * Mm, 256, 0, stream>>>(featsT, xyz, new_xyz, idx,
                                            W1b, b1e, W2b, b2e, out);
}

// Round 19
// 152.698 us; speedup vs baseline: 1.2201x; 1.1353x over previous
//
#include <hip/hip_runtime.h>
#include <stdint.h>

typedef __bf16 bf16x8 __attribute__((ext_vector_type(8)));
typedef float f32x4 __attribute__((ext_vector_type(4)));

#define NSAMPLE 64
static constexpr int Bb = 4, Nn = 16384, Mm = 1024, Cc = 256;
static constexpr int K1P = 288;   // layer-1 K: 256 features + 3 coords + pad (9 x 32)

__device__ __forceinline__ unsigned short f2bf(float f) {
  unsigned int u = __builtin_bit_cast(unsigned int, f);
  u = u + 0x7fffu + ((u >> 16) & 1u);
  return (unsigned short)(u >> 16);
}

// async global->LDS, 16B per lane; LDS dest = wave-uniform base + lane*16
__device__ __forceinline__ void gload_lds16(const void* g, void* lds) {
  __builtin_amdgcn_global_load_lds(
      (const __attribute__((address_space(1))) uint32_t*)g,
      (__attribute__((address_space(3))) uint32_t*)lds, 16, 0, 0);
}

// ---- ALL helpers in ONE kernel, block-range partitioned:
// blocks 0..1023: ballq, 4 QUERIES PER BLOCK sharing point loads (L2 traffic /4), split-scan
//   across 4 waves (wave w scans quarter w for all 4 queries); per-(query,wave) ordered hit
//   lists merged by 256 threads. d2 op order identical to reference (bit-identical results).
// blocks 1024..5119: featsT (R8-verbatim).
// blocks 5120..5407: prep (R1-verbatim).
__global__ void helpers_kernel(const float* __restrict__ xyz,
                               const float* __restrict__ new_xyz,
                               const float* __restrict__ feats,
                               const float* __restrict__ W1, const float* __restrict__ b1,
                               const float* __restrict__ g1, const float* __restrict__ be1,
                               const float* __restrict__ m1, const float* __restrict__ v1,
                               const float* __restrict__ W2, const float* __restrict__ b2,
                               const float* __restrict__ g2, const float* __restrict__ be2,
                               const float* __restrict__ m2, const float* __restrict__ v2,
                               unsigned short* __restrict__ W1b, float* __restrict__ b1e,
                               unsigned short* __restrict__ W2b, float* __restrict__ b2e,
                               unsigned short* __restrict__ featsT,
                               int* __restrict__ idx) {
  __shared__ float tile[64][65];
  __shared__ int wl[4][4][64];   // [query][wave][slot]
  __shared__ int wcnt[4][4];     // [query][wave]
  int bx = blockIdx.x;
  int t = threadIdx.x;
  if (bx < 1024) {
    const float r2 = (float)(0.08 * 0.08);
    int bm0 = bx * 4;            // queries bm0..bm0+3, same batch (4 | 1024)
    int lane = t & 63, w = t >> 6;
    int b = bm0 >> 10;
    float qx[4], qy[4], qz[4], qq[4];
    int cnt[4];
#pragma unroll
    for (int qi = 0; qi < 4; qi++) {
      qx[qi] = new_xyz[(bm0 + qi) * 3];
      qy[qi] = new_xyz[(bm0 + qi) * 3 + 1];
      qz[qi] = new_xyz[(bm0 + qi) * 3 + 2];
      qq[qi] = __fadd_rn(__fadd_rn(__fmul_rn(qx[qi], qx[qi]), __fmul_rn(qy[qi], qy[qi])),
                         __fmul_rn(qz[qi], qz[qi]));
      cnt[qi] = 0;
    }
    const float* P = xyz + ((size_t)b * Nn + w * 4096) * 3;
    for (int n0 = 0; n0 < 4096; n0 += 64) {
      const float* pp = P + (n0 + lane) * 3;
      float x = pp[0], y = pp[1], z = pp[2];
      float p2 = __fadd_rn(__fadd_rn(__fmul_rn(x, x), __fmul_rn(y, y)), __fmul_rn(z, z));
#pragma unroll
      for (int qi = 0; qi < 4; qi++) {
        if (cnt[qi] >= NSAMPLE) continue;   // wave-uniform (cnt identical across lanes)
        float dt = __fadd_rn(__fadd_rn(__fmul_rn(qx[qi], x), __fmul_rn(qy[qi], y)),
                             __fmul_rn(qz[qi], z));
        float d2 = __fsub_rn(__fadd_rn(qq[qi], p2), __fmul_rn(2.f, dt));
        bool valid = d2 < r2;
        unsigned long long mask = __ballot(valid);
        if (mask) {
          if (valid) {
            int pos = cnt[qi] + __popcll(mask & ((1ull << lane) - 1ull));
            if (pos < NSAMPLE) wl[qi][w][pos] = w * 4096 + n0 + lane;
          }
          cnt[qi] += (int)__popcll(mask);
        }
      }
      if (cnt[0] >= NSAMPLE && cnt[1] >= NSAMPLE && cnt[2] >= NSAMPLE && cnt[3] >= NSAMPLE)
        break;
    }
    if (lane == 0) {
#pragma unroll
      for (int qi = 0; qi < 4; qi++) wcnt[qi][w] = cnt[qi];
    }
    __syncthreads();
    {
      int qi = t >> 6, s = t & 63;   // 256 threads = 4 queries x 64 slots
      int c0 = wcnt[qi][0], c1 = wcnt[qi][1], c2 = wcnt[qi][2], c3 = wcnt[qi][3];
      int tot = c0 + c1 + c2 + c3;
      int cc = tot < NSAMPLE ? tot : NSAMPLE;
      int v;
      if (s < cc) {
        if (s < c0) v = wl[qi][0][s];
        else if (s < c0 + c1) v = wl[qi][1][s - c0];
        else if (s < c0 + c1 + c2) v = wl[qi][2][s - c0 - c1];
        else v = wl[qi][3][s - c0 - c1 - c2];
      } else {
        v = (c0 > 0) ? wl[qi][0][0] : (c1 > 0) ? wl[qi][1][0]
          : (c2 > 0) ? wl[qi][2][0] : (c3 > 0) ? wl[qi][3][0] : 0;
      }
      idx[(size_t)(bm0 + qi) * NSAMPLE + s] = v;
    }
    return;
  }
  if (bx < 5120) {
    // ---------------- featsT — R8 verbatim body ----------------
    int fb = bx - 1024;             // 0..4095
    int b = fb >> 10;
    int rem = fb & 1023;
    int nt = rem >> 2, ct = rem & 3;
    int tx = t & 63, ty = t >> 6;
    const float* src = feats + ((size_t)b * Cc + ct * 64) * Nn + nt * 64;
#pragma unroll
    for (int i = 0; i < 16; i++) {
      int c = i * 4 + ty;
      tile[c][tx] = src[(size_t)c * Nn + tx];
    }
    __syncthreads();
    unsigned short* dst = featsT + ((size_t)b * Nn + nt * 64) * Cc + ct * 64;
    int c4 = (t & 15) * 4, n0 = t >> 4;
#pragma unroll
    for (int i = 0; i < 4; i++) {
      int n = i * 16 + n0;
      ushort4 v;
      v.x = f2bf(tile[c4][n]);
      v.y = f2bf(tile[c4 + 1][n]);
      v.z = f2bf(tile[c4 + 2][n]);
      v.w = f2bf(tile[c4 + 3][n]);
      *(ushort4*)&dst[(size_t)n * Cc + c4] = v;
    }
    return;
  }
  // ---------------- prep body (R1 verbatim, t from local block range) ----------------
  int g = (bx - 5120) * 256 + t;
  if (g < 256 * K1P) {
    int o = g / K1P, k = g - o * K1P;
    float s = g1[o] / sqrtf(v1[o] + 1e-5f);
    float w = 0.f;
    if (k < 256) w = W1[o * 259 + 3 + k];
    else if (k < 259) w = W1[o * 259 + (k - 256)];
    W1b[g] = f2bf(w * s);
  }
  if (g < 256 * 256) {
    int o = g >> 8;
    float s = g2[o] / sqrtf(v2[o] + 1e-5f);
    W2b[g] = f2bf(W2[g] * s);
  }
  if (g < 256) {
    float s1 = g1[g] / sqrtf(v1[g] + 1e-5f);
    b1e[g] = s1 * (b1[g] - m1[g]) + be1[g];
    float s2 = g2[g] / sqrtf(v2[g] + 1e-5f);
    b2e[g] = s2 * (b2[g] - m2[g]) + be2[g];
  }
}

// ---------------- fused: R18 body, setprio removed (m190: negative on lockstep waves),
// ---------------- gather issued before coord chain (HBM flight overlaps coord VALU) ----------
__global__ __launch_bounds__(256, 4) void fused_kernel(
    const unsigned short* __restrict__ featsT, const float* __restrict__ xyz,
    const float* __restrict__ new_xyz, const int* __restrict__ idx,
    const unsigned short* __restrict__ W1b, const float* __restrict__ b1e,
    const unsigned short* __restrict__ W2b, const float* __restrict__ b2e,
    float* __restrict__ out) {
  __shared__ unsigned short Xf[64 * 256];  // 32768 B, swizzled feature tile / H tile
  __shared__ unsigned short Xco[64 * 40];  // 5120 B, coord K-chunk
  int t = threadIdx.x;
  int wave = t >> 6, lane = t & 63;
  int lr = lane & 15, kg = lane >> 4;
  int wcol = wave * 64;
  int bm = blockIdx.x;
  int b = bm >> 10;

  {
    int idxr = idx[(size_t)bm * NSAMPLE + wave * 16 + (lane & 15)];
#pragma unroll
    for (int i = 0; i < 8; i++) {
      int j = wave * 8 + i;                       // row pair 2j, 2j+1
      int iv = __shfl(idxr, 2 * i + (lane >> 5));
      int r7 = (2 * j + (lane >> 5)) & 7;
      int cg = (lane & 31) ^ r7;                  // swizzled global chunk (rule #21)
      gload_lds16(featsT + ((size_t)b * Nn + iv) * Cc + cg * 8, &Xf[j * 512]);
    }
  }
  if (t < 64) {
    int ci = idx[(size_t)bm * NSAMPLE + t];
    const float* pp = xyz + ((size_t)b * Nn + ci) * 3;
    float px = pp[0], py = pp[1], pz = pp[2];
    unsigned int c01 = (unsigned int)f2bf(px - new_xyz[bm * 3])
                     | ((unsigned int)f2bf(py - new_xyz[bm * 3 + 1]) << 16);
    unsigned int c2 = (unsigned int)f2bf(pz - new_xyz[bm * 3 + 2]);
    uint4 v0 = make_uint4(c01, c2, 0u, 0u);
    uint4 z = make_uint4(0u, 0u, 0u, 0u);
    uint4* row = (uint4*)&Xco[t * 40];
    row[0] = v0; row[1] = z; row[2] = z; row[3] = z; row[4] = z;
  }
  __syncthreads();

  // ---- layer 1: [64x288]x[288x256]; kk 0..7 from Xf (swizzled), kk 8 from Xco ----
  f32x4 acc[4][4];
#pragma unroll
  for (int mi = 0; mi < 4; mi++)
#pragma unroll
    for (int ni = 0; ni < 4; ni++) acc[mi][ni] = (f32x4){0.f, 0.f, 0.f, 0.f};
  {
    bf16x8 w[2][4];
#pragma unroll
    for (int ni = 0; ni < 4; ni++)
      w[0][ni] = *(const bf16x8*)&W1b[(size_t)(wcol + ni * 16 + lr) * K1P + kg * 8];
#pragma unroll
    for (int kk = 0; kk < 9; kk++) {
      int cur = kk & 1, nxt = cur ^ 1;
      if (kk < 8) {
#pragma unroll
        for (int ni = 0; ni < 4; ni++)
          w[nxt][ni] =
              *(const bf16x8*)&W1b[(size_t)(wcol + ni * 16 + lr) * K1P + (kk + 1) * 32 + kg * 8];
      }
      bf16x8 a[4];
#pragma unroll
      for (int mi = 0; mi < 4; mi++) {
        int r = mi * 16 + lr;
        if (kk < 8) {
          int cs = ((kk * 4 + kg) ^ (r & 7)) * 8;
          a[mi] = *(const bf16x8*)&Xf[r * 256 + cs];
        } else {
          a[mi] = *(const bf16x8*)&Xco[r * 40 + kg * 8];
        }
      }
#pragma unroll
      for (int mi = 0; mi < 4; mi++)
#pragma unroll
        for (int ni = 0; ni < 4; ni++)
          acc[mi][ni] =
              __builtin_amdgcn_mfma_f32_16x16x32_bf16(a[mi], w[cur][ni], acc[mi][ni], 0, 0, 0);
    }
  }
  __syncthreads();  // B3

#pragma unroll
  for (int ni = 0; ni < 4; ni++) {
    int o = wcol + ni * 16 + lr;
    float bb = b1e[o];
#pragma unroll
    for (int mi = 0; mi < 4; mi++)
#pragma unroll
      for (int j = 0; j < 4; j++) {
        int r = mi * 16 + kg * 4 + j;
        float h = fmaxf(acc[mi][ni][j] + bb, 0.f);
        Xf[r * 256 + ((((o >> 3) ^ (r & 7)) << 3) + (o & 7))] = f2bf(h);
      }
  }
  __syncthreads();  // B4

  // ---- layer 2: [64x256]x[256x256] from H (same swizzle), same W double-buffer ----
#pragma unroll
  for (int mi = 0; mi < 4; mi++)
#pragma unroll
    for (int ni = 0; ni < 4; ni++) acc[mi][ni] = (f32x4){0.f, 0.f, 0.f, 0.f};
  {
    bf16x8 w[2][4];
#pragma unroll
    for (int ni = 0; ni < 4; ni++)
      w[0][ni] = *(const bf16x8*)&W2b[(size_t)(wcol + ni * 16 + lr) * 256 + kg * 8];
#pragma unroll
    for (int kk = 0; kk < 8; kk++) {
      int cur = kk & 1, nxt = cur ^ 1;
      if (kk < 7) {
#pragma unroll
        for (int ni = 0; ni < 4; ni++)
          w[nxt][ni] =
              *(const bf16x8*)&W2b[(size_t)(wcol + ni * 16 + lr) * 256 + (kk + 1) * 32 + kg * 8];
      }
      bf16x8 a[4];
#pragma unroll
      for (int mi = 0; mi < 4; mi++) {
        int r = mi * 16 + lr;
        int cs = ((kk * 4 + kg) ^ (r & 7)) * 8;
        a[mi] = *(const bf16x8*)&Xf[r * 256 + cs];
      }
#pragma unroll
      for (int mi = 0; mi < 4; mi++)
#pragma unroll
        for (int ni = 0; ni < 4; ni++)
          acc[mi][ni] =
              __builtin_amdgcn_mfma_f32_16x16x32_bf16(a[mi], w[cur][ni], acc[mi][ni], 0, 0, 0);
    }
  }
  {
    int m = bm & (Mm - 1);
#pragma unroll
    for (int ni = 0; ni < 4; ni++) {
      float bv = b2e[wcol + ni * 16 + lr];
      float v = 0.f;  // relu(max) == max(relu)
#pragma unroll
      for (int mi = 0; mi < 4; mi++)
#pragma unroll
        for (int j = 0; j < 4; j++) v = fmaxf(v, acc[mi][ni][j] + bv);
      v = fmaxf(v, __shfl_xor(v, 16));
      v = fmaxf(v, __shfl_xor(v, 32));
      if (kg == 0)
        out[((size_t)b * 256 + wcol + ni * 16 + lr) * Mm + m] = v;
    }
  }
}

extern "C" void kernel_launch(void* const* d_in, const int* in_sizes, int n_in,
                              void* d_out, int out_size, void* d_ws, size_t ws_size,
                              hipStream_t stream) {
  (void)in_sizes; (void)n_in; (void)out_size; (void)ws_size;
  const float* xyz     = (const float*)d_in[0];
  const float* new_xyz = (const float*)d_in[1];
  const float* feats   = (const float*)d_in[2];
  const float* W1 = (const float*)d_in[3];
  const float* b1 = (const float*)d_in[4];
  const float* g1 = (const float*)d_in[5];
  const float* be1 = (const float*)d_in[6];
  const float* m1 = (const float*)d_in[7];
  const float* v1 = (const float*)d_in[8];
  const float* W2 = (const float*)d_in[9];
  const float* b2 = (const float*)d_in[10];
  const float* g2 = (const float*)d_in[11];
  const float* be2 = (const float*)d_in[12];
  const float* m2 = (const float*)d_in[13];
  const float* v2 = (const float*)d_in[14];
  float* out = (float*)d_out;

  char* ws = (char*)d_ws;
  unsigned short* W1b   = (unsigned short*)(ws + 0);         // 147456 B ([256][288])
  unsigned short* W2b   = (unsigned short*)(ws + 147456);    // 131072 B
  float*          b1e   = (float*)(ws + 278528);             // 1024 B
  float*          b2e   = (float*)(ws + 279552);             // 1024 B
  unsigned short* featsT= (unsigned short*)(ws + 280576);    // 33554432 B
  int*            idx   = (int*)(ws + 33835008);             // 1048576 B (end ~34.9 MB)

  helpers_kernel<<<1024 + 4096 + 288, 256, 0, stream>>>(
      xyz, new_xyz, feats, W1, b1, g1, be1, m1, v1, W2, b2, g2, be2, m2, v2,
      W1b, b1e, W2b, b2e, featsT, idx);
  fused_kernel<<<Bb * Mm, 256, 0, stream>>>(featsT, xyz, new_xyz, idx,
                                            W1b, b1e, W2b, b2e, out);
}